// Round 3
// baseline (529.282 us; speedup 1.0000x reference)
//
#include <hip/hip_runtime.h>
#include <math.h>

#define NT 65536
#define EE 1048576
#define NB 128
#define KK 410          // kept nodes per graph = ceil(0.8*512)
#define HH 128

typedef short bf16x8 __attribute__((ext_vector_type(8)));
typedef float f32x4 __attribute__((ext_vector_type(4)));
typedef unsigned int u32x4 __attribute__((ext_vector_type(4)));

// ---------------- device scratch -------------------------------------------
__device__ __align__(16) unsigned short g_xb[(size_t)NT * 64];    // x bf16 row-major (conv1 root)
__device__ __align__(16) unsigned short g_hb1[(size_t)NT * HH];
__device__ __align__(16) unsigned short g_hb2[(size_t)NT * HH];
__device__ __align__(16) unsigned short g_wt1[128 * 128];
__device__ __align__(16) unsigned short g_wtc[3 * 128 * 256];
__device__ __align__(16) unsigned short g_xbs[(size_t)8 * NT * 8];   // x slice-major [slice][node][8]
__device__ __align__(16) unsigned short g_hbs[(size_t)8 * NT * 16];  // h slice-major [slice][node][16] (reused h1 -> gated h2 -> h3)
__device__ __align__(16) unsigned short g_agg[(size_t)16 * NT * 8];  // agg slice-major [group8][node][8]
__device__ unsigned short g_csr1u[EE];   // src id per edge, grouped by dst
__device__ unsigned short g_keptu[NT];   // 1 if node kept by SAGPool
__device__ unsigned int g_ebuck[EE];     // packed (dstLocal<<16)|src, bucketed by graph
__device__ int g_bcnt[128];
__device__ int g_bbase[129];
__device__ int g_bcur[128];
__device__ float g_trel[NT];
__device__ float g_troot[NT];
__device__ float g_gatef[NT];            // tanh(score) if kept else 0
__device__ float g_kinv[NT];             // 1/max(kept-neighbor count,1)
__device__ float g_xc4[4 * NB * 4 * 128]; // pooled partials [sec][graph][quarter][128]
__device__ int g_rows1[NT + 1];

__device__ __forceinline__ unsigned short* ubuf(int id) {
    switch (id) {
        case 0: return g_xb;
        case 1: return g_hb1;
        case 2: return g_hb2;
        case 3: return g_wt1;
        case 4: return g_wtc;
    }
    return g_xb;
}

__device__ __forceinline__ float b2f(unsigned short u) {
    union { unsigned int i; float f; } v;
    v.i = ((unsigned int)u) << 16;
    return v.f;
}
__device__ __forceinline__ unsigned short f2b(float f) {
    unsigned int x = __float_as_uint(f);
    unsigned int r = x + 0x7fffu + ((x >> 16) & 1u);   // round-to-nearest-even
    return (unsigned short)(r >> 16);
}
__device__ __forceinline__ unsigned int pk2(float a, float b) {
    return (unsigned int)f2b(a) | ((unsigned int)f2b(b) << 16);
}
__device__ __forceinline__ unsigned int mul2(unsigned int wd, float g) {
    float lo = b2f((unsigned short)(wd & 0xffffu)) * g;
    float hi = b2f((unsigned short)(wd >> 16)) * g;
    return pk2(lo, hi);
}
__device__ __forceinline__ bf16x8 scale8(bf16x8 a, float g) {
    bf16x8 r;
#pragma unroll
    for (int i = 0; i < 8; i++) {
        unsigned short u = (unsigned short)a[i];
        r[i] = (short)f2b(b2f(u) * g);
    }
    return r;
}

// ---------------- prep: x->bf16 (row+slice major), weights, zero bcnt -------
// NOTE (R7): no grid-wide fences on CDNA4 (per-XCD L2) — kernel boundaries sync.
__global__ void k_prep(const float* __restrict__ x,
                       const float* __restrict__ W1r, const float* __restrict__ W1o,
                       const float* __restrict__ Wcr, const float* __restrict__ Wco) {
    int tid = blockIdx.x * 256 + threadIdx.x;
    if (tid < 1048576) {
        float4 v = *(const float4*)&x[(size_t)tid * 4];
        unsigned int lo = pk2(v.x, v.y);
        unsigned int hi = pk2(v.z, v.w);
        *(uint2*)&g_xb[(size_t)tid * 4] = make_uint2(lo, hi);
        // slice-major copy: node = tid>>4, f0 = (tid&15)*4, slice = f0>>3
        int node = tid >> 4;
        int sl = (tid & 15) >> 1;
        int of = (tid & 1) * 4;
        *(uint2*)&g_xbs[(((size_t)sl) * NT + node) * 8 + of] = make_uint2(lo, hi);
    } else if (tid < 1048576 + 16384) {
        int r = tid - 1048576;
        int k = r & 127, n = r >> 7;
        float v = (k < 64) ? W1r[k * 128 + n] : W1o[(k - 64) * 128 + n];
        g_wt1[n * 128 + k] = f2b(v);
    } else if (tid < 1048576 + 16384 + 98304) {
        int r = tid - (1048576 + 16384);
        int l = r >> 15;
        int k = r & 255, n = (r >> 8) & 127;
        float v = (k < 128) ? Wcr[l * 16384 + k * 128 + n]
                            : Wco[l * 16384 + (k - 128) * 128 + n];
        g_wtc[l * 32768 + n * 256 + k] = f2b(v);
    } else if (tid < 1048576 + 16384 + 98304 + 128) {
        g_bcnt[tid - (1048576 + 16384 + 98304)] = 0;
    }
}

// ---------------- CSR1 build: 2-level counting sort -------------------------
__global__ __launch_bounds__(256) void k_bhist(const int* __restrict__ dst) {
    __shared__ int h[128];
    if (threadIdx.x < 128) h[threadIdx.x] = 0;
    __syncthreads();
    int e0 = (blockIdx.x * 256 + threadIdx.x) * 4;
    int4 d = *(const int4*)&dst[e0];
    atomicAdd(&h[d.x >> 9], 1);
    atomicAdd(&h[d.y >> 9], 1);
    atomicAdd(&h[d.z >> 9], 1);
    atomicAdd(&h[d.w >> 9], 1);
    __syncthreads();
    if (threadIdx.x < 128 && h[threadIdx.x]) atomicAdd(&g_bcnt[threadIdx.x], h[threadIdx.x]);
}

__global__ __launch_bounds__(128) void k_bscan() {
    __shared__ int s[128];
    int t = threadIdx.x;
    int v = g_bcnt[t];
    s[t] = v;
    __syncthreads();
    for (int off = 1; off < 128; off <<= 1) {
        int u = (t >= off) ? s[t - off] : 0;
        __syncthreads();
        s[t] += u;
        __syncthreads();
    }
    g_bbase[t] = s[t] - v;
    g_bcur[t] = s[t] - v;
    if (t == 127) g_bbase[128] = s[127];
}

__global__ __launch_bounds__(256) void k_bscatter(const int* __restrict__ src,
                                                  const int* __restrict__ dst) {
    __shared__ int h[128];
    __shared__ int base[128];
    if (threadIdx.x < 128) h[threadIdx.x] = 0;
    __syncthreads();
    int e0 = (blockIdx.x * 256 + threadIdx.x) * 4;
    int4 s = *(const int4*)&src[e0];
    int4 d = *(const int4*)&dst[e0];
    int b0 = d.x >> 9, b1 = d.y >> 9, b2 = d.z >> 9, b3 = d.w >> 9;
    atomicAdd(&h[b0], 1);
    atomicAdd(&h[b1], 1);
    atomicAdd(&h[b2], 1);
    atomicAdd(&h[b3], 1);
    __syncthreads();
    if (threadIdx.x < 128) {
        int c = h[threadIdx.x];
        base[threadIdx.x] = c ? atomicAdd(&g_bcur[threadIdx.x], c) : 0;
        h[threadIdx.x] = 0;
    }
    __syncthreads();
    int r0 = atomicAdd(&h[b0], 1);
    g_ebuck[base[b0] + r0] = ((unsigned int)(d.x & 511) << 16) | (unsigned int)s.x;
    int r1 = atomicAdd(&h[b1], 1);
    g_ebuck[base[b1] + r1] = ((unsigned int)(d.y & 511) << 16) | (unsigned int)s.y;
    int r2 = atomicAdd(&h[b2], 1);
    g_ebuck[base[b2] + r2] = ((unsigned int)(d.z & 511) << 16) | (unsigned int)s.z;
    int r3 = atomicAdd(&h[b3], 1);
    g_ebuck[base[b3] + r3] = ((unsigned int)(d.w & 511) << 16) | (unsigned int)s.w;
}

__global__ __launch_bounds__(512) void k_bcsr() {
    __shared__ int hist[512];
    __shared__ int offs[512];
    __shared__ int cur[512];
    int g = blockIdx.x, t = threadIdx.x;
    hist[t] = 0;
    cur[t] = 0;
    __syncthreads();
    int b0 = g_bbase[g], b1 = g_bbase[g + 1];
    for (int e = b0 + t; e < b1; e += 512) {
        unsigned int p = g_ebuck[e];
        atomicAdd(&hist[p >> 16], 1);
    }
    __syncthreads();
    int v = hist[t];
    offs[t] = v;
    __syncthreads();
    for (int off = 1; off < 512; off <<= 1) {
        int u = (t >= off) ? offs[t - off] : 0;
        __syncthreads();
        offs[t] += u;
        __syncthreads();
    }
    int excl = offs[t] - v;
    g_rows1[g * 512 + t] = b0 + excl;
    if (t == 511) g_rows1[g * 512 + 512] = b0 + excl + v;
    __syncthreads();
    offs[t] = excl;
    __syncthreads();
    for (int e = b0 + t; e < b1; e += 512) {
        unsigned int p = g_ebuck[e];
        int dl = p >> 16;
        int r = atomicAdd(&cur[dl], 1);
        g_csr1u[b0 + offs[dl] + r] = (unsigned short)(p & 0xFFFFu);
    }
}

// ---------------- sliced gather-aggregate -----------------------------------
// R8+R9 post-mortem: fused-gather convs were pinned at ~86us regardless of
// occupancy (R8 2x: null) or bytes (R9 fp8 halved FETCH: null). Request rate
// was ~constant ~10G random row-requests/s => bound by beyond-L2 random
// request throughput. Fix: make gathers L2-HITS. Operand stored slice-major
// ([slice][node][F feats]); block's slice = blockIdx&7 so under round-robin
// block->XCD dispatch each XCD touches only its own 1-2MB slice (fits 4MB L2).
// Pure layout trick: wrong mapping degrades perf only, never correctness.
// One lane per dst node; fp32 accum in e-ascending order (bit-identical to
// the old fused path for conv1/2 => top-k selection preserved exactly).
#define ACCP(wd, J) { acc[J] += b2f((unsigned short)((wd) & 0xffffu)); acc[(J) + 1] += b2f((unsigned short)((wd) >> 16)); }
#define ACCQ(q, B) ACCP(q.x, B) ACCP(q.y, (B) + 2) ACCP(q.z, (B) + 4) ACCP(q.w, (B) + 6)

template <int F, int DEN>   // F feats/slice (8 or 16); DEN: 0 = 1/deg, 1 = g_kinv
__global__ __launch_bounds__(256) void k_agg(int srcId) {
    const unsigned short* src = (srcId == 0) ? g_xbs : g_hbs;
    int s = blockIdx.x & 7;
    int node = (blockIdx.x >> 3) * 256 + threadIdx.x;
    const unsigned short* sp = src + (size_t)s * NT * F;
    int r0 = g_rows1[node], r1 = g_rows1[node + 1];
    float inv;
    if (DEN) {
        inv = g_kinv[node];
    } else {
        int c = r1 - r0;
        inv = 1.0f / (float)(c > 0 ? c : 1);
    }
    float acc[F];
#pragma unroll
    for (int i = 0; i < F; i++) acc[i] = 0.f;
    int e = r0;
    for (; e + 2 <= r1; e += 2) {
        int i0 = g_csr1u[e], i1 = g_csr1u[e + 1];
        if constexpr (F == 16) {
            uint4 a0 = *(const uint4*)&sp[(size_t)i0 * 16];
            uint4 a1 = *(const uint4*)&sp[(size_t)i0 * 16 + 8];
            uint4 b0 = *(const uint4*)&sp[(size_t)i1 * 16];
            uint4 b1 = *(const uint4*)&sp[(size_t)i1 * 16 + 8];
            ACCQ(a0, 0) ACCQ(a1, 8) ACCQ(b0, 0) ACCQ(b1, 8)
        } else {
            uint4 a0 = *(const uint4*)&sp[(size_t)i0 * 8];
            uint4 b0 = *(const uint4*)&sp[(size_t)i1 * 8];
            ACCQ(a0, 0) ACCQ(b0, 0)
        }
    }
    for (; e < r1; e++) {
        int i0 = g_csr1u[e];
        if constexpr (F == 16) {
            uint4 a0 = *(const uint4*)&sp[(size_t)i0 * 16];
            uint4 a1 = *(const uint4*)&sp[(size_t)i0 * 16 + 8];
            ACCQ(a0, 0) ACCQ(a1, 8)
        } else {
            uint4 a0 = *(const uint4*)&sp[(size_t)i0 * 8];
            ACCQ(a0, 0)
        }
    }
    // scale + pack + nontemporal store (keep resident slice lines in L2)
    int gb = (F == 16) ? (2 * s) : s;
    u32x4 o;
    o[0] = pk2(acc[0] * inv, acc[1] * inv);
    o[1] = pk2(acc[2] * inv, acc[3] * inv);
    o[2] = pk2(acc[4] * inv, acc[5] * inv);
    o[3] = pk2(acc[6] * inv, acc[7] * inv);
    __builtin_nontemporal_store(o, (u32x4*)&g_agg[((size_t)gb * NT + node) * 8]);
    if constexpr (F == 16) {
        u32x4 o2;
        o2[0] = pk2(acc[8] * inv, acc[9] * inv);
        o2[1] = pk2(acc[10] * inv, acc[11] * inv);
        o2[2] = pk2(acc[12] * inv, acc[13] * inv);
        o2[3] = pk2(acc[14] * inv, acc[15] * inv);
        __builtin_nontemporal_store(o2, (u32x4*)&g_agg[((size_t)(2 * s + 1) * NT + node) * 8]);
    }
}

// ---------------- kinv precompute (kept-neighbor counts, post-topk) ---------
__global__ __launch_bounds__(256) void k_kinv() {
    int node = blockIdx.x * 256 + threadIdx.x;
    int r0 = g_rows1[node], r1 = g_rows1[node + 1];
    int kc = 0;
    for (int e = r0; e < r1; e++) kc += (int)g_keptu[g_csr1u[e]];
    g_kinv[node] = 1.0f / (float)(kc > 0 ? kc : 1);
}

// ---------------- gate premultiply: hb2 row-major -> gated slice-major ------
__global__ __launch_bounds__(256) void k_gateS() {
    int tid = blockIdx.x * 256 + threadIdx.x;   // over NT*8
    int n = tid >> 3, s = tid & 7;
    float g = g_gatef[n];
    const unsigned short* srcp = &g_hb2[(size_t)n * 128 + s * 16];
    uint4 a = *(const uint4*)srcp;
    uint4 b = *(const uint4*)(srcp + 8);
    uint4 oa, ob;
    oa.x = mul2(a.x, g); oa.y = mul2(a.y, g); oa.z = mul2(a.z, g); oa.w = mul2(a.w, g);
    ob.x = mul2(b.x, g); ob.y = mul2(b.y, g); ob.z = mul2(b.z, g); ob.w = mul2(b.w, g);
    unsigned short* d = &g_hbs[((size_t)s * NT + n) * 16];
    *(uint4*)d = oa;
    *(uint4*)(d + 8) = ob;
}

// ---------------- MFMA conv: out = relu([agg | root] @ W + bias) ------------
// A-half streamed from g_agg (slice-major bf16), root from row-major buffer
// (BGATE: scaled by gate), MASKED rows zeroed. Epilogues: pool partials ->
// g_xc4; DOTS -> g_trel/g_troot; WSL -> slice-major copy for next gather.
template <int KA, int KB, int MASKED, int DOTS, int BGATE, int WSL>
__global__ __launch_bounds__(256) void k_mm(int bId, int wId, int wOfs,
                                            const float* __restrict__ bias, int outId, int sec,
                                            const float* __restrict__ pwr,
                                            const float* __restrict__ pwt) {
    __shared__ float s[128];
    const unsigned short* Bp = ubuf(bId);
    const unsigned short* Wt = ubuf(wId) + wOfs;
    unsigned short* out = ubuf(outId);
    int rowbase = blockIdx.x * 128;
    const int K = KA + KB;
    int lane = threadIdx.x & 63;
    int w = threadIdx.x >> 6;
    int n16 = lane & 15, quad = lane >> 4;
    int rowloc = w * 32;
    int rowg = rowbase + rowloc;
    int g = blockIdx.x >> 2, qb = blockIdx.x & 3;
    float ga0 = BGATE ? g_gatef[rowg + n16] : 1.0f;
    float ga1 = BGATE ? g_gatef[rowg + 16 + n16] : 1.0f;
    f32x4 acc[2][8];
#pragma unroll
    for (int rt = 0; rt < 2; rt++)
#pragma unroll
        for (int ct = 0; ct < 8; ct++)
#pragma unroll
            for (int i = 0; i < 4; i++) acc[rt][ct][i] = 0.f;

#pragma unroll
    for (int ks = 0; ks < K / 32; ks++) {
        int k0 = ks * 32;
        bf16x8 a0, a1;
        if (k0 < KA) {
            int fg = (k0 + quad * 8) >> 3;
            a0 = *(const bf16x8*)&g_agg[((size_t)fg * NT + rowg + n16) * 8];
            a1 = *(const bf16x8*)&g_agg[((size_t)fg * NT + rowg + 16 + n16) * 8];
        } else {
            int kk = k0 - KA;
            a0 = *(const bf16x8*)&Bp[(size_t)(rowg + n16) * KB + kk + quad * 8];
            a1 = *(const bf16x8*)&Bp[(size_t)(rowg + 16 + n16) * KB + kk + quad * 8];
            if (BGATE) { a0 = scale8(a0, ga0); a1 = scale8(a1, ga1); }
        }
#pragma unroll
        for (int ct = 0; ct < 8; ct++) {
            bf16x8 b = *(const bf16x8*)&Wt[(size_t)(ct * 16 + n16) * K + k0 + quad * 8];
            acc[0][ct] = __builtin_amdgcn_mfma_f32_16x16x32_bf16(a0, b, acc[0][ct], 0, 0, 0);
            acc[1][ct] = __builtin_amdgcn_mfma_f32_16x16x32_bf16(a1, b, acc[1][ct], 0, 0, 0);
        }
    }

    // bias + relu + mask, store (row-major + optional slice-major copy)
    if (threadIdx.x < 128) s[threadIdx.x] = 0.f;
#pragma unroll
    for (int rt = 0; rt < 2; rt++) {
        float m[4];
#pragma unroll
        for (int i = 0; i < 4; i++) {
            int r = rowg + rt * 16 + quad * 4 + i;
            m[i] = (!MASKED || g_keptu[r]) ? 1.0f : 0.0f;
        }
#pragma unroll
        for (int ct = 0; ct < 8; ct++) {
            int c = ct * 16 + n16;
            float bv = bias[c];
#pragma unroll
            for (int i = 0; i < 4; i++) {
                int r = rowg + rt * 16 + quad * 4 + i;
                float v = fmaxf(acc[rt][ct][i] + bv, 0.f) * m[i];
                acc[rt][ct][i] = v;
                unsigned short hv = f2b(v);
                out[(size_t)r * 128 + c] = hv;
                if (WSL) g_hbs[((size_t)(c >> 4) * NT + r) * 16 + (c & 15)] = hv;
            }
        }
    }
    __syncthreads();

    // pool epilogue: column sums over this block's 128 rows
#pragma unroll
    for (int ct = 0; ct < 8; ct++) {
        float p = 0.f;
#pragma unroll
        for (int rt = 0; rt < 2; rt++)
#pragma unroll
            for (int i = 0; i < 4; i++) p += acc[rt][ct][i];
        p += __shfl_xor(p, 16);
        p += __shfl_xor(p, 32);
        if (quad == 0) atomicAdd(&s[ct * 16 + n16], p);
    }

    // DOTS epilogue (conv2): row dots with pwr/pwt
    if (DOTS) {
        float pr[8], pt[8];
#pragma unroll
        for (int ct = 0; ct < 8; ct++) {
            pr[ct] = pwr[ct * 16 + n16];
            pt[ct] = pwt[ct * 16 + n16];
        }
#pragma unroll
        for (int rt = 0; rt < 2; rt++)
#pragma unroll
            for (int i = 0; i < 4; i++) {
                float dr = 0.f, dt = 0.f;
#pragma unroll
                for (int ct = 0; ct < 8; ct++) {
                    dr += acc[rt][ct][i] * pr[ct];
                    dt += acc[rt][ct][i] * pt[ct];
                }
                dr += __shfl_xor(dr, 1); dt += __shfl_xor(dt, 1);
                dr += __shfl_xor(dr, 2); dt += __shfl_xor(dt, 2);
                dr += __shfl_xor(dr, 4); dt += __shfl_xor(dt, 4);
                dr += __shfl_xor(dr, 8); dt += __shfl_xor(dt, 8);
                if (n16 == 0) {
                    int r = rowg + rt * 16 + quad * 4 + i;
                    g_trel[r] = dr;
                    g_troot[r] = dt;
                }
            }
    }
    __syncthreads();
    if (threadIdx.x < 128)
        g_xc4[((sec * NB + g) * 4 + qb) * 128 + threadIdx.x] = s[threadIdx.x];
}

// ---------------- SAGPool: fused score + per-graph bitonic top-410 ----------
__global__ __launch_bounds__(256) void k_topk(const float* __restrict__ pb) {
    __shared__ float sv[512];
    __shared__ int si[512];
    int g = blockIdx.x, t = threadIdx.x;
    float pbv = pb[0];
    for (int l = t; l < 512; l += 256) {
        int node = g * 512 + l;
        int r0 = g_rows1[node], r1 = g_rows1[node + 1];
        float s = 0.f;
        int e = r0;
        for (; e + 4 <= r1; e += 4) {
            float s0 = g_trel[g_csr1u[e]];
            float s1 = g_trel[g_csr1u[e + 1]];
            float s2 = g_trel[g_csr1u[e + 2]];
            float s3 = g_trel[g_csr1u[e + 3]];
            s += (s0 + s1) + (s2 + s3);
        }
        for (; e < r1; e++) s += g_trel[g_csr1u[e]];
        sv[l] = s + g_troot[node] + pbv;
        si[l] = l;
    }
    __syncthreads();
    for (int k = 2; k <= 512; k <<= 1) {
        for (int j = k >> 1; j > 0; j >>= 1) {
            for (int i = t; i < 512; i += 256) {
                int p = i ^ j;
                if (p > i) {
                    float va = sv[i], vb = sv[p];
                    int ia = si[i], ib = si[p];
                    bool aFirst = (va > vb) || (va == vb && ia < ib);
                    bool up = ((i & k) == 0);
                    if (up != aFirst) { sv[i] = vb; sv[p] = va; si[i] = ib; si[p] = ia; }
                }
            }
            __syncthreads();
        }
    }
    for (int r = t; r < 512; r += 256) {
        int old = g * 512 + si[r];
        if (r < KK) {
            g_gatef[old] = tanhf(sv[r]);
            g_keptu[old] = 1;
        } else {
            g_gatef[old] = 0.f;
            g_keptu[old] = 0;
        }
    }
}

// ---------------- MLP head + log_softmax ------------------------------------
__global__ __launch_bounds__(128) void k_head(const float* __restrict__ W1, const float* __restrict__ b1,
                                              const float* __restrict__ W2, const float* __restrict__ b2,
                                              float* __restrict__ out) {
    __shared__ float xr[512];
    __shared__ float r0[128], r1[128];
    int g = blockIdx.x, t = threadIdx.x;
    for (int i = t; i < 512; i += 128) {
        int sec = i >> 7, c = i & 127;
        const float* p = &g_xc4[((sec * NB + g) * 4) * 128 + c];
        float v = p[0] + p[128] + p[256] + p[384];
        float inv = (sec < 2) ? (1.0f / 512.0f) : (1.0f / 410.0f);
        xr[i] = v * inv;
    }
    __syncthreads();
    float acc = b1[t];
    for (int k = 0; k < 512; k++) acc += xr[k] * W1[k * 128 + t];
    acc = fmaxf(acc, 0.f);
    r0[t] = acc * W2[t * 2 + 0];
    r1[t] = acc * W2[t * 2 + 1];
    __syncthreads();
    for (int off = 64; off > 0; off >>= 1) {
        if (t < off) { r0[t] += r0[t + off]; r1[t] += r1[t + off]; }
        __syncthreads();
    }
    if (t == 0) {
        float z0 = r0[0] + b2[0], z1 = r1[0] + b2[1];
        float m = fmaxf(z0, z1);
        float l = m + logf(expf(z0 - m) + expf(z1 - m));
        out[g * 2 + 0] = z0 - l;
        out[g * 2 + 1] = z1 - l;
    }
}

// ---------------- launch -----------------------------------------------------
extern "C" void kernel_launch(void* const* d_in, const int* in_sizes, int n_in,
                              void* d_out, int out_size, void* d_ws, size_t ws_size,
                              hipStream_t stream) {
    const float* x = (const float*)d_in[0];
    const int* ei = (const int*)d_in[1];
    const int* src = ei;
    const int* dst = ei + EE;
    const float* W1r = (const float*)d_in[3];
    const float* W1o = (const float*)d_in[4];
    const float* b1 = (const float*)d_in[5];
    const float* Wcr = (const float*)d_in[6];
    const float* Wco = (const float*)d_in[7];
    const float* bc = (const float*)d_in[8];
    const float* pwr = (const float*)d_in[9];
    const float* pwt = (const float*)d_in[10];
    const float* pb = (const float*)d_in[11];
    const float* l1W = (const float*)d_in[12];
    const float* l1b = (const float*)d_in[13];
    const float* l2W = (const float*)d_in[14];
    const float* l2b = (const float*)d_in[15];
    float* out = (float*)d_out;

    // ---- prep (x->bf16 row+slice, weights->bf16, zero bcnt) ----
    k_prep<<<(1048576 + 16384 + 98304 + 128 + 255) / 256, 256, 0, stream>>>(x, W1r, W1o, Wcr, Wco);

    // ---- CSR1 via counting sort (fence-free: kernel boundaries do the sync) ----
    k_bhist<<<1024, 256, 0, stream>>>(dst);
    k_bscan<<<1, 128, 0, stream>>>();
    k_bscatter<<<1024, 256, 0, stream>>>(src, dst);
    k_bcsr<<<128, 512, 0, stream>>>();

    // ---- conv1: sliced agg(xbs) -> mm([agg|xb]@wt1) -> hb1 (+h1 slices); sec0 ----
    k_agg<8, 0><<<2048, 256, 0, stream>>>(0);
    k_mm<64, 64, 0, 0, 0, 1><<<512, 256, 0, stream>>>(0, 3, 0, b1, 1, 0, pwr, pwt);

    // ---- conv2: sliced agg(h1 slices) -> mm -> hb2; DOTS; sec1 ----
    k_agg<16, 0><<<2048, 256, 0, stream>>>(1);
    k_mm<128, 128, 0, 1, 0, 0><<<512, 256, 0, stream>>>(1, 4, 0, bc, 2, 1, pwr, pwt);

    // ---- SAGPool: fused score + top-410 -> gatef/keptu (bit-exact path) ----
    k_topk<<<NB, 256, 0, stream>>>(pb);
    k_kinv<<<NT / 256, 256, 0, stream>>>();
    k_gateS<<<2048, 256, 0, stream>>>();

    // ---- conv3: agg(gated h2 slices, kinv) -> mm (BGATE root, MASKED) -> hb1 (+h3 slices); sec2 ----
    k_agg<16, 1><<<2048, 256, 0, stream>>>(1);
    k_mm<128, 128, 1, 0, 1, 1><<<512, 256, 0, stream>>>(2, 4, 32768, bc + 128, 1, 2, pwr, pwt);

    // ---- conv4: agg(h3 slices, kinv) -> mm (MASKED) -> hb2; sec3 ----
    k_agg<16, 1><<<2048, 256, 0, stream>>>(1);
    k_mm<128, 128, 1, 0, 0, 0><<<512, 256, 0, stream>>>(1, 4, 65536, bc + 256, 2, 3, pwr, pwt);

    // ---- head ----
    k_head<<<NB, 128, 0, stream>>>(l1W, l1b, l2W, l2b, out);
}